// Round 4
// baseline (123.237 us; speedup 1.0000x reference)
//
#include <hip/hip_runtime.h>
#include <hip/hip_bf16.h>

// Problem constants
#define BATCH 16384
#define GATES 1023
#define NPAD  1024
#define OUTF  128

typedef unsigned short ushortT;
typedef short bf16x8 __attribute__((ext_vector_type(8)));
typedef float f32x4 __attribute__((ext_vector_type(4)));

__device__ inline float bf2f(ushortT u) {
    union { unsigned int i; float f; } v;
    v.i = ((unsigned int)u) << 16;
    return v.f;
}
__device__ inline ushortT f2bf(float f) {
    union { float f; unsigned int i; } v;
    v.f = f;
    unsigned int x = v.i;
    unsigned int r = (x + 0x7FFFu + ((x >> 16) & 1u)) >> 16;  // RNE
    return (ushortT)r;
}

// async global->LDS, 16B/lane; lds base wave-uniform, HW writes base + lane*16.
__device__ inline void gl2lds16(const void* gptr, void* ldsptr) {
    __builtin_amdgcn_global_load_lds(
        (const __attribute__((address_space(1))) void*)gptr,
        (__attribute__((address_space(3))) void*)ldsptr, 16, 0, 0);
}

// fine-grained VMEM wait (AITER-style); memory clobber pins ds_read after it
#define WAITVM(N) asm volatile("s_waitcnt vmcnt(" #N ")" ::: "memory")

// ---------------- prep: gwT (transpose+pad), gbp, zh ----------------
__global__ void k_prep(const float* __restrict__ gw, const float* __restrict__ gb,
                       const float* __restrict__ z, ushortT* __restrict__ gwT,
                       float* __restrict__ gbp, ushortT* __restrict__ zh) {
    const int b = blockIdx.x, t = threadIdx.x;
    if (b < 1024) {
        int id = b * 256 + t;
        int n = id >> 8, k = id & 255;
        float v = (n < GATES) ? gw[k * GATES + n] : 0.f;
        gwT[n * 256 + k] = f2bf(v);
        if (id < NPAD) gbp[id] = (id < GATES) ? gb[id] : 0.f;
    } else {
        int i = (b - 1024) * 256 + t;
        const float4* p = (const float4*)z + (size_t)i * 2;
        float4 a = p[0], c = p[1];
        ushortT o[8] = {f2bf(a.x), f2bf(a.y), f2bf(a.z), f2bf(a.w),
                        f2bf(c.x), f2bf(c.y), f2bf(c.z), f2bf(c.w)};
        *(bf16x8*)(zh + (size_t)i * 8) = *(bf16x8*)o;
    }
}

// ---------------- mega: x -> gatings -> leaves -> out; 32 rows/block ----------------
// Barrier-free K-loops: per-wave private LDS ring (3 x 4KB) + s_waitcnt vmcnt(N).
// sG layout: [row][1024 slots] halfwords, 16B-chunk XOR swizzle (row>>1)&7.
//   gating i at slot i+1  => depth-d tree nodes occupy aligned 2^d blocks
//   leaf  k at slot k     => P3 A-fragments are aligned b128 chunks
__global__ __launch_bounds__(256, 1) void k_mega(const float* __restrict__ x,
                                                 const ushortT* __restrict__ gwT,
                                                 const float* __restrict__ gbp,
                                                 const ushortT* __restrict__ zh,
                                                 float* __restrict__ out) {
    __shared__ ushortT sG[32 * 1024];   // 64 KB
    __shared__ ushortT sW[4 * 3 * 2048];// 48 KB: 4 waves x 3 ring bufs x 4 KB

    const int tid = threadIdx.x;
    const int wave = tid >> 6, lane = tid & 63;
    const int quad = lane >> 4, l15 = lane & 15;
    const int bm = blockIdx.x * 32;
    const int lrow = lane >> 2, lcol = (lane & 3) * 8;
    ushortT* sWw = sW + wave * 3 * 2048;

    auto sgaddr = [](int row, int slot) -> int {
        return row * 1024 + ((((slot >> 3) ^ ((row >> 1) & 7)) << 3) | (slot & 7));
    };

    // ---- preload A (x rows -> bf16 frags) and bias; drain vmcnt for clean pipeline
    bf16x8 af[2][8];
#pragma unroll
    for (int mt = 0; mt < 2; ++mt) {
        const float* xr = x + (size_t)(bm + mt * 16 + l15) * 256 + quad * 8;
#pragma unroll
        for (int c = 0; c < 8; ++c) {
            float4 a = *(const float4*)(xr + c * 32);
            float4 b = *(const float4*)(xr + c * 32 + 4);
            ushortT o[8] = {f2bf(a.x), f2bf(a.y), f2bf(a.z), f2bf(a.w),
                            f2bf(b.x), f2bf(b.y), f2bf(b.z), f2bf(b.w)};
            af[mt][c] = *(bf16x8*)o;
        }
    }
    const int Nw = wave * 256;  // this wave's 256-col slice of the 1024 gates
    float bias[4][4];
#pragma unroll
    for (int g = 0; g < 4; ++g)
#pragma unroll
        for (int j = 0; j < 4; ++j)
            bias[g][j] = gbp[Nw + g * 64 + j * 16 + l15];
    WAITVM(0);

    // ---- P1: gatings = sigmoid(x @ gw + gb); wave-private pipelined staging ----
    // chunk c (0..31): cols Nw + (c>>3)*64 .. +63, k = (c&7)*32 .. +31  (4 KB)
    auto issueP1 = [&](int c, int b) {
        const ushortT* src = gwT + (size_t)(Nw + (c >> 3) * 64 + lrow) * 256 +
                             (c & 7) * 32 + lcol;
        ushortT* dst = sWw + b * 2048;
#pragma unroll
        for (int e = 0; e < 4; ++e)
            gl2lds16(src + (size_t)(e * 16) * 256, dst + e * 512);
    };
    issueP1(0, 0);
    issueP1(1, 1);
    for (int g = 0; g < 4; ++g) {
        f32x4 acc[2][4] = {};
#pragma unroll
        for (int kc = 0; kc < 8; ++kc) {
            const int c = g * 8 + kc;
            if (kc < 6) {           // c <= 29 always
                issueP1(c + 2, (c + 2) % 3);
                WAITVM(8);
            } else if (kc == 6) {
                if (g < 3) { issueP1(c + 2, (c + 2) % 3); WAITVM(8); }
                else WAITVM(4);
            } else {
                if (g < 3) { issueP1(c + 2, (c + 2) % 3); WAITVM(8); }
                else WAITVM(0);
            }
            const ushortT* buf = sWw + (c % 3) * 2048;
#pragma unroll
            for (int j = 0; j < 4; ++j) {
                bf16x8 bfrag = *(const bf16x8*)(buf + j * 512 + l15 * 32 + quad * 8);
                acc[0][j] = __builtin_amdgcn_mfma_f32_16x16x32_bf16(af[0][kc], bfrag,
                                                                    acc[0][j], 0, 0, 0);
                acc[1][j] = __builtin_amdgcn_mfma_f32_16x16x32_bf16(af[1][kc], bfrag,
                                                                    acc[1][j], 0, 0, 0);
            }
        }
        // epilogue: sigmoid -> sG (gating col at slot col+1; padded col 1023 -> slot 0)
#pragma unroll
        for (int mt = 0; mt < 2; ++mt) {
            int row0 = mt * 16 + quad * 4;
#pragma unroll
            for (int j = 0; j < 4; ++j) {
                int col = Nw + g * 64 + j * 16 + l15;
                float bv = bias[g][j];
                int slot = (col < GATES) ? (col + 1) : 0;
#pragma unroll
                for (int r = 0; r < 4; ++r) {
                    float gt = 1.f / (1.f + __expf(-(acc[mt][j][r] + bv)));
                    sG[sgaddr(row0 + r, slot)] = f2bf(gt);
                }
            }
        }
    }
    __syncthreads();

    // ---- P2: tree; all reads vectorized & aligned via the +1-shifted layout ----
    for (int rr = 0; rr < 8; ++rr) {
        const int row = wave * 8 + rr;
        // loads (independent; issued up-front)
        ushortT p[6];
#pragma unroll
        for (int d = 0; d < 6; ++d)
            p[d] = sG[sgaddr(row, (1 << d) + (lane >> (6 - d)))];
        ushortT q0 = sG[sgaddr(row, 64 + lane)];
        unsigned int q1 = *(const unsigned int*)(sG + sgaddr(row, 128 + 2 * lane));
        uint2 q2 = *(const uint2*)(sG + sgaddr(row, 256 + 4 * lane));
        bf16x8 q3 = *(const bf16x8*)(sG + sgaddr(row, 512 + 8 * lane));
        // prefix over depths 0..5
        float P = 1.f;
#pragma unroll
        for (int d = 0; d < 6; ++d) {
            float gv = bf2f(p[d]);
            P *= ((lane >> (5 - d)) & 1) ? (1.f - gv) : gv;
        }
        float v[16];
        {   // depth 6 (1 gate)
            float gv = bf2f(q0);
            float a = P * gv;
            v[0] = a; v[1] = P - a;
        }
        {   // depth 7 (2 gates), t descending
            float g1 = bf2f((ushortT)(q1 >> 16));
            float a1 = v[1] * g1; v[3] = v[1] - a1; v[2] = a1;
            float g0 = bf2f((ushortT)(q1 & 0xFFFF));
            float a0 = v[0] * g0; v[1] = v[0] - a0; v[0] = a0;
        }
        {   // depth 8 (4 gates), t descending
            ushortT gs[4] = {(ushortT)(q2.x & 0xFFFF), (ushortT)(q2.x >> 16),
                             (ushortT)(q2.y & 0xFFFF), (ushortT)(q2.y >> 16)};
#pragma unroll
            for (int t = 3; t >= 0; --t) {
                float gv = bf2f(gs[t]);
                float a = v[t] * gv;
                v[2 * t + 1] = v[t] - a;
                v[2 * t] = a;
            }
        }
        {   // depth 9 (8 gates), t descending
#pragma unroll
            for (int t = 7; t >= 0; --t) {
                float gv = bf2f((ushortT)q3[t]);
                float a = v[t] * gv;
                v[2 * t + 1] = v[t] - a;
                v[2 * t] = a;
            }
        }
        ushortT o[16];
#pragma unroll
        for (int t = 0; t < 16; ++t) o[t] = f2bf(v[t]);
        // leaves at slots lane*16 .. +15 (chunk-aligned b128 x2, conflict-free)
        *(bf16x8*)(sG + sgaddr(row, lane * 16))     = *(bf16x8*)o;
        *(bf16x8*)(sG + sgaddr(row, lane * 16 + 8)) = *(bf16x8*)(o + 8);
    }
    __syncthreads();

    // ---- P3: out = leaf @ z^T; wave-private pipelined staging of z slice ----
    const int colw = wave * 32;
    auto issueP3 = [&](int c, int b) {
        const ushortT* src = zh + (size_t)(colw + lrow) * 1024 + c * 64 + lcol;
        ushortT* dst = sWw + b * 2048;
#pragma unroll
        for (int e = 0; e < 2; ++e)
#pragma unroll
            for (int kc = 0; kc < 2; ++kc)
                gl2lds16(src + (size_t)(e * 16) * 1024 + kc * 32,
                         dst + kc * 1024 + e * 512);
    };
    issueP3(0, 0);
    issueP3(1, 1);
    f32x4 oacc[2][2] = {};
    for (int c = 0; c < 16; ++c) {
        if (c < 14) { issueP3(c + 2, (c + 2) % 3); WAITVM(8); }
        else if (c == 14) { WAITVM(4); }
        else { WAITVM(0); }
        const ushortT* buf = sWw + (c % 3) * 2048;
#pragma unroll
        for (int ks = 0; ks < 2; ++ks) {
            bf16x8 a0 = *(const bf16x8*)(sG + sgaddr(l15,      c * 64 + ks * 32 + quad * 8));
            bf16x8 a1 = *(const bf16x8*)(sG + sgaddr(16 + l15, c * 64 + ks * 32 + quad * 8));
#pragma unroll
            for (int j = 0; j < 2; ++j) {
                bf16x8 bfrag = *(const bf16x8*)(buf + ks * 1024 + j * 512 +
                                                l15 * 32 + quad * 8);
                oacc[0][j] = __builtin_amdgcn_mfma_f32_16x16x32_bf16(a0, bfrag,
                                                                     oacc[0][j], 0, 0, 0);
                oacc[1][j] = __builtin_amdgcn_mfma_f32_16x16x32_bf16(a1, bfrag,
                                                                     oacc[1][j], 0, 0, 0);
            }
        }
    }
    // epilogue: C/D row = quad*4 + reg, col = l15
#pragma unroll
    for (int mt = 0; mt < 2; ++mt) {
        int gm = bm + mt * 16 + quad * 4;
#pragma unroll
        for (int j = 0; j < 2; ++j) {
            int gn = colw + j * 16 + l15;
#pragma unroll
            for (int r = 0; r < 4; ++r)
                out[(size_t)(gm + r) * OUTF + gn] = oacc[mt][j][r];
        }
    }
}

// ---------------- launch ----------------
extern "C" void kernel_launch(void* const* d_in, const int* in_sizes, int n_in,
                              void* d_out, int out_size, void* d_ws, size_t ws_size,
                              hipStream_t stream) {
    const float* x  = (const float*)d_in[0];   // 16384 x 256
    const float* gw = (const float*)d_in[1];   // 256 x 1023
    const float* gb = (const float*)d_in[2];   // 1023
    const float* z  = (const float*)d_in[3];   // 128 x 1024
    float* out = (float*)d_out;                // 16384 x 128

    char* ws = (char*)d_ws;
    ushortT* gwT = (ushortT*)(ws + 0);       // 524,288 B
    ushortT* zh  = (ushortT*)(ws + 524288);  // 262,144 B
    float*   gbp = (float*)  (ws + 786432);  //   4,096 B

    k_prep<<<1088, 256, 0, stream>>>(gw, gb, z, gwT, gbp, zh);
    k_mega<<<512, 256, 0, stream>>>(x, gwT, gbp, zh, out);
}

// Round 6
// 119.648 us; speedup vs baseline: 1.0300x; 1.0300x over previous
//
#include <hip/hip_runtime.h>
#include <hip/hip_bf16.h>

// Problem constants
#define BATCH 16384
#define GATES 1023
#define NPAD  1024
#define OUTF  128

typedef unsigned short ushortT;
typedef short bf16x8 __attribute__((ext_vector_type(8)));
typedef float f32x4 __attribute__((ext_vector_type(4)));

__device__ inline float bf2f(ushortT u) {
    union { unsigned int i; float f; } v;
    v.i = ((unsigned int)u) << 16;
    return v.f;
}
__device__ inline ushortT f2bf(float f) {
    union { float f; unsigned int i; } v;
    v.f = f;
    unsigned int x = v.i;
    unsigned int r = (x + 0x7FFFu + ((x >> 16) & 1u)) >> 16;  // RNE
    return (ushortT)r;
}

// async global->LDS, 16B/lane; lds base wave-uniform, HW writes base + lane*16.
__device__ inline void gl2lds16(const void* gptr, void* ldsptr) {
    __builtin_amdgcn_global_load_lds(
        (const __attribute__((address_space(1))) void*)gptr,
        (__attribute__((address_space(3))) void*)ldsptr, 16, 0, 0);
}

#define WAITVM(N) asm volatile("s_waitcnt vmcnt(" #N ")" ::: "memory")
// Drain ALL ds ops before re-issuing into a ring buffer: guarantees no ds_read
// of the buffer being overwritten is still in the LDS pipe when the VMEM
// return lands (the R5 corruption mechanism — waitcnt pass runs post-sched,
// so MFMA+lgkm-wait can sink below the next issue without this).
#define WAITLGKM  asm volatile("s_waitcnt lgkmcnt(0)" ::: "memory")
#define MEMFENCE  asm volatile("" ::: "memory")

// ---------------- prep ----------------
// blocks [0,64):   gw (256x1023 f32) -> gwT (1024x256 bf16) via LDS-bounce transpose
// blocks [64,128): z -> zh bf16
// block 128:       gb -> gbp padded
__global__ void k_prep(const float* __restrict__ gw, const float* __restrict__ gb,
                       const float* __restrict__ z, ushortT* __restrict__ gwT,
                       float* __restrict__ gbp, ushortT* __restrict__ zh) {
    const int b = blockIdx.x, t = threadIdx.x;
    if (b < 64) {
        __shared__ ushortT sT[256 * 17];
        const int nb = b * 16, nloc = t & 15, kb = t >> 4;  // 16 n-cols x 256 k
#pragma unroll
        for (int kk = 0; kk < 16; ++kk) {
            int k = kk * 16 + kb;
            int n = nb + nloc;
            float v = (n < GATES) ? gw[(size_t)k * GATES + n] : 0.f;  // coalesced
            sT[k * 17 + nloc] = f2bf(v);
        }
        __syncthreads();
#pragma unroll
        for (int nn = 0; nn < 16; ++nn)
            gwT[(size_t)(nb + nn) * 256 + t] = sT[t * 17 + nn];  // coalesced
    } else if (b < 128) {
        int i = (b - 64) * 256 + t;  // 16384 groups of 8
        const float4* p = (const float4*)z + (size_t)i * 2;
        float4 a = p[0], c = p[1];
        ushortT o[8] = {f2bf(a.x), f2bf(a.y), f2bf(a.z), f2bf(a.w),
                        f2bf(c.x), f2bf(c.y), f2bf(c.z), f2bf(c.w)};
        *(bf16x8*)(zh + (size_t)i * 8) = *(bf16x8*)o;
    } else {
#pragma unroll
        for (int u = 0; u < 4; ++u) {
            int i = t * 4 + u;
            gbp[i] = (i < GATES) ? gb[i] : 0.f;
        }
    }
}

// ---------------- mega: x -> gatings -> leaves -> out; 32 rows/block, 8 waves -------
// Per-wave private ring pipelines (3 x 2KB, vmcnt-paced, lgkm-guarded, barrier-free):
//   P1: wave w computes cols {slab*256 + w*32 .. +31}; stages its own gwT slice.
//   P3: wave w computes out cols {w*16 .. +15}; stages its own z slice.
// Only 2 __syncthreads (P1->P2, P2->P3). 112 KB LDS, 512 thr -> 2 waves/SIMD.
// sG layout: [row][1024 slots], 16B-chunk XOR swizzle (row>>1)&7; gate i at slot i+1,
// leaf k at slot k (in-place overwrite per row is wave-lockstep safe).
__global__ __launch_bounds__(512, 2) void k_mega(const float* __restrict__ x,
                                                 const ushortT* __restrict__ gwT,
                                                 const float* __restrict__ gbp,
                                                 const ushortT* __restrict__ zh,
                                                 float* __restrict__ out) {
    __shared__ ushortT sG[32 * 1024];    // 64 KB
    __shared__ ushortT sW[8 * 3 * 1024]; // 48 KB: 8 waves x ring of 3 x 2KB

    const int tid = threadIdx.x;
    const int wave = tid >> 6, lane = tid & 63;
    const int quad = lane >> 4, l15 = lane & 15;
    const int bm = blockIdx.x * 32;
    const int lrow = lane >> 2, lcol = (lane & 3) * 8;
    ushortT* rW = sW + wave * 3 * 1024;

    auto sgaddr = [](int row, int slot) -> int {
        return row * 1024 + ((((slot >> 3) ^ ((row >> 1) & 7)) << 3) | (slot & 7));
    };

    const int colw = wave * 32;  // P1: wave's col base within each 256-col slab

    // P1 chunk c = s*8 + kc: cols [s*256+colw, +32), k [kc*32, +32)  (2 KB)
    auto issue1 = [&](int c) {
        WAITLGKM;  // ring-reuse guard (see macro comment)
        int s = c >> 3, kc = c & 7;
        const ushortT* src = gwT + (size_t)(s * 256 + colw + lrow) * 256 + kc * 32 + lcol;
        ushortT* dst = rW + (c % 3) * 1024;
        gl2lds16(src, dst);
        gl2lds16(src + 16 * 256, dst + 512);
    };

    issue1(0);
    issue1(1);
    MEMFENCE;

    // ---- preload x -> af (grouped to cap VGPR pressure), bias ----
    bf16x8 af[2][8];
    float bias[4][2];
#pragma unroll
    for (int mt = 0; mt < 2; ++mt) {
        const float* xr = x + (size_t)(bm + mt * 16 + l15) * 256 + quad * 8;
#pragma unroll
        for (int c = 0; c < 8; ++c) {
            float4 a = *(const float4*)(xr + c * 32);
            float4 b = *(const float4*)(xr + c * 32 + 4);
            ushortT o[8] = {f2bf(a.x), f2bf(a.y), f2bf(a.z), f2bf(a.w),
                            f2bf(b.x), f2bf(b.y), f2bf(b.z), f2bf(b.w)};
            af[mt][c] = *(bf16x8*)o;
        }
        MEMFENCE;  // keep the two 16-load groups from merging
    }
#pragma unroll
    for (int s = 0; s < 4; ++s)
#pragma unroll
        for (int jn = 0; jn < 2; ++jn)
            bias[s][jn] = gbp[s * 256 + colw + jn * 16 + l15];

    // ---- P1: barrier-free per-wave pipeline over 32 chunks ----
    f32x4 acc[2][2];
#pragma unroll
    for (int c = 0; c < 32; ++c) {
        if (c + 2 < 32) issue1(c + 2);
        if (c <= 29) { WAITVM(4); }
        else if (c == 30) { WAITVM(2); }
        else { WAITVM(0); }
        if ((c & 7) == 0) {
#pragma unroll
            for (int mt = 0; mt < 2; ++mt)
#pragma unroll
                for (int jn = 0; jn < 2; ++jn)
                    acc[mt][jn] = (f32x4){0.f, 0.f, 0.f, 0.f};
        }
        const ushortT* buf = rW + (c % 3) * 1024;
        const int kc = c & 7;
        bf16x8 b0 = *(const bf16x8*)(buf + l15 * 32 + quad * 8);
        bf16x8 b1 = *(const bf16x8*)(buf + 512 + l15 * 32 + quad * 8);
        acc[0][0] = __builtin_amdgcn_mfma_f32_16x16x32_bf16(af[0][kc], b0, acc[0][0], 0, 0, 0);
        acc[1][0] = __builtin_amdgcn_mfma_f32_16x16x32_bf16(af[1][kc], b0, acc[1][0], 0, 0, 0);
        acc[0][1] = __builtin_amdgcn_mfma_f32_16x16x32_bf16(af[0][kc], b1, acc[0][1], 0, 0, 0);
        acc[1][1] = __builtin_amdgcn_mfma_f32_16x16x32_bf16(af[1][kc], b1, acc[1][1], 0, 0, 0);
        if ((c & 7) == 7) {
            const int s = c >> 3;
#pragma unroll
            for (int mt = 0; mt < 2; ++mt) {
                int row0 = mt * 16 + quad * 4;
#pragma unroll
                for (int jn = 0; jn < 2; ++jn) {
                    int col = s * 256 + colw + jn * 16 + l15;
                    float bv = bias[s][jn];
                    int slot = (col < GATES) ? (col + 1) : 0;  // pad col -> unused slot 0
#pragma unroll
                    for (int r = 0; r < 4; ++r) {
                        float gt = 1.f / (1.f + __expf(-(acc[mt][jn][r] + bv)));
                        sG[sgaddr(row0 + r, slot)] = f2bf(gt);
                    }
                }
            }
        }
    }
    __syncthreads();

    // ---- P3 prefetch prologue (lands during P2) ----
    auto issue3 = [&](int c) {
        WAITLGKM;  // ring-reuse guard
        const ushortT* src = zh + (size_t)(wave * 16 + lrow) * 1024 + c * 64 + lcol;
        ushortT* dst = rW + (c % 3) * 1024;
        gl2lds16(src, dst);
        gl2lds16(src + 32, dst + 512);
    };
    issue3(0);
    issue3(1);
    MEMFENCE;

    // ---- P2: tree, 4 rows/wave, all LDS (vectorized via +1-shift layout) ----
#pragma unroll
    for (int rr = 0; rr < 4; ++rr) {
        const int row = wave * 4 + rr;
        ushortT p[6];
#pragma unroll
        for (int d = 0; d < 6; ++d)
            p[d] = sG[sgaddr(row, (1 << d) + (lane >> (6 - d)))];
        ushortT q0 = sG[sgaddr(row, 64 + lane)];
        unsigned int q1 = *(const unsigned int*)(sG + sgaddr(row, 128 + 2 * lane));
        uint2 q2 = *(const uint2*)(sG + sgaddr(row, 256 + 4 * lane));
        bf16x8 q3 = *(const bf16x8*)(sG + sgaddr(row, 512 + 8 * lane));
        float P = 1.f;
#pragma unroll
        for (int d = 0; d < 6; ++d) {
            float gv = bf2f(p[d]);
            P *= ((lane >> (5 - d)) & 1) ? (1.f - gv) : gv;
        }
        float v[16];
        {
            float gv = bf2f(q0);
            float a = P * gv;
            v[0] = a; v[1] = P - a;
        }
        {
            float g1 = bf2f((ushortT)(q1 >> 16));
            float a1 = v[1] * g1; v[3] = v[1] - a1; v[2] = a1;
            float g0 = bf2f((ushortT)(q1 & 0xFFFF));
            float a0 = v[0] * g0; v[1] = v[0] - a0; v[0] = a0;
        }
        {
            ushortT gs[4] = {(ushortT)(q2.x & 0xFFFF), (ushortT)(q2.x >> 16),
                             (ushortT)(q2.y & 0xFFFF), (ushortT)(q2.y >> 16)};
#pragma unroll
            for (int t = 3; t >= 0; --t) {
                float gv = bf2f(gs[t]);
                float a = v[t] * gv;
                v[2 * t + 1] = v[t] - a;
                v[2 * t] = a;
            }
        }
        {
#pragma unroll
            for (int t = 7; t >= 0; --t) {
                float gv = bf2f((ushortT)q3[t]);
                float a = v[t] * gv;
                v[2 * t + 1] = v[t] - a;
                v[2 * t] = a;
            }
        }
        ushortT o[16];
#pragma unroll
        for (int t = 0; t < 16; ++t) o[t] = f2bf(v[t]);
        *(bf16x8*)(sG + sgaddr(row, lane * 16))     = *(bf16x8*)o;
        *(bf16x8*)(sG + sgaddr(row, lane * 16 + 8)) = *(bf16x8*)(o + 8);
    }
    __syncthreads();

    // ---- P3: out = leaf @ z^T; per-wave pipeline over 16 chunks (64 k each) ----
    f32x4 oacc[2] = {};
#pragma unroll
    for (int c = 0; c < 16; ++c) {
        if (c + 2 < 16) issue3(c + 2);
        if (c <= 13) { WAITVM(4); }
        else if (c == 14) { WAITVM(2); }
        else { WAITVM(0); }
        const ushortT* buf = rW + (c % 3) * 1024;
#pragma unroll
        for (int ks = 0; ks < 2; ++ks) {
            bf16x8 b0 = *(const bf16x8*)(buf + ks * 512 + l15 * 32 + quad * 8);
            bf16x8 a0 = *(const bf16x8*)(sG + sgaddr(l15,      c * 64 + ks * 32 + quad * 8));
            bf16x8 a1 = *(const bf16x8*)(sG + sgaddr(16 + l15, c * 64 + ks * 32 + quad * 8));
            oacc[0] = __builtin_amdgcn_mfma_f32_16x16x32_bf16(a0, b0, oacc[0], 0, 0, 0);
            oacc[1] = __builtin_amdgcn_mfma_f32_16x16x32_bf16(a1, b0, oacc[1], 0, 0, 0);
        }
    }
    // epilogue: C/D row = quad*4 + reg, col = l15
#pragma unroll
    for (int mt = 0; mt < 2; ++mt) {
        int gm = bm + mt * 16 + quad * 4;
        int gn = wave * 16 + l15;
#pragma unroll
        for (int r = 0; r < 4; ++r)
            out[(size_t)(gm + r) * OUTF + gn] = oacc[mt][r];
    }
}

// ---------------- launch ----------------
extern "C" void kernel_launch(void* const* d_in, const int* in_sizes, int n_in,
                              void* d_out, int out_size, void* d_ws, size_t ws_size,
                              hipStream_t stream) {
    const float* x  = (const float*)d_in[0];   // 16384 x 256
    const float* gw = (const float*)d_in[1];   // 256 x 1023
    const float* gb = (const float*)d_in[2];   // 1023
    const float* z  = (const float*)d_in[3];   // 128 x 1024
    float* out = (float*)d_out;                // 16384 x 128

    char* ws = (char*)d_ws;
    ushortT* gwT = (ushortT*)(ws + 0);       // 524,288 B
    ushortT* zh  = (ushortT*)(ws + 524288);  // 262,144 B
    float*   gbp = (float*)  (ws + 786432);  //   4,096 B

    k_prep<<<129, 256, 0, stream>>>(gw, gb, z, gwT, gbp, zh);
    k_mega<<<512, 512, 0, stream>>>(x, gwT, gbp, zh, out);
}